// Round 8
// baseline (244.725 us; speedup 1.0000x reference)
//
#include <hip/hip_runtime.h>
#include <hip/hip_bf16.h>

#define B_  512
#define L_  100
#define LP_ 112      // rows padded to 7*16
#define LQ_ 128      // HT row length (j padded)
#define D_  128
#define SH_ 136      // prep LDS ushort stride
#define SP_ 136      // Pt ushort stride

#define HWS_BYTES  (512ULL * LP_ * D_ * 2ULL)          // 14,680,064
#define HT_OFFSET  HWS_BYTES                            // total ws use: 31,457,280 B (fits: R5 ran this)

typedef unsigned short ushort_t;
typedef __attribute__((ext_vector_type(8))) unsigned short us8;
typedef __attribute__((ext_vector_type(8))) __bf16 bf8;
typedef __attribute__((ext_vector_type(4))) float f4;
typedef __attribute__((ext_vector_type(4))) float f4v;
typedef __attribute__((ext_vector_type(4))) unsigned int ui4;

__device__ __forceinline__ float b2f(ushort_t u) {
  union { unsigned i; float f; } v; v.i = ((unsigned)u) << 16; return v.f;
}
__device__ __forceinline__ ushort_t f2b(float f) {
  unsigned u = __float_as_uint(f);
  u += 0x7fffu + ((u >> 16) & 1u);   // RNE
  return (ushort_t)(u >> 16);
}
__device__ __forceinline__ us8 pack8(const float* x) {
  union { __hip_bfloat162 h; unsigned u; } cv;
  ui4 pk;
#pragma unroll
  for (int t = 0; t < 4; ++t) {
    cv.h = __float22bfloat162_rn(make_float2(x[2 * t], x[2 * t + 1]));
    pk[t] = cv.u;
  }
  return __builtin_bit_cast(us8, pk);
}
// XOR-swizzled Hs index (16B chunks contiguous; chunk ^= row&15)
__device__ __forceinline__ int sw(int row, int col) {
  return row * 128 + ((((col >> 3) ^ row) & 15) << 3) + (col & 7);
}

// ---------------- kernel 1: gather + transpose into workspace (R5-proven) ----------------
__global__ __launch_bounds__(256, 4)
void prep_kernel(const int* __restrict__ inp, const float* __restrict__ embF,
                 ushort_t* __restrict__ Hws, ushort_t* __restrict__ HTws) {
  __shared__ __align__(16) ushort_t Hs[LQ_ * SH_];   // rows 100..127 zero
  const int b = blockIdx.x, tid = threadIdx.x;

  for (int u = tid; u < LQ_ * 16; u += 256) {
    int r = u >> 4, ch = u & 15;
    us8 o = {0, 0, 0, 0, 0, 0, 0, 0};
    if (r < L_) {
      int idx = inp[b * L_ + r];
      const float* src = embF + ((size_t)idx << 7) + ch * 8;
      f4v v0 = *(const f4v*)src;
      f4v v1 = *(const f4v*)(src + 4);
      float x[8];
#pragma unroll
      for (int t = 0; t < 4; ++t) { x[t] = v0[t]; x[4 + t] = v1[t]; }
      o = pack8(x);
    }
    *(us8*)&Hs[r * SH_ + ch * 8] = o;
    if (r < LP_) *(us8*)(Hws + (size_t)b * LP_ * D_ + r * D_ + ch * 8) = o;
  }
  __syncthreads();

  for (int u = tid; u < D_ * 16; u += 256) {
    int d = u & 127, jch = u >> 7;
    us8 vv;
#pragma unroll
    for (int t = 0; t < 8; ++t) vv[t] = Hs[(jch * 8 + t) * SH_ + d];
    *(us8*)(HTws + (size_t)b * D_ * LQ_ + d * LQ_ + jch * 8) = vv;
  }
}

// ---------------- kernel 2: attention — dense feeds, ONE barrier ----------------
// 512 blocks x 448 thr (7 waves); wave w owns M-tile w (rows w*16..w*16+15).
__global__ __launch_bounds__(448, 4)
void attn_kernel(const int* __restrict__ adjG,
                 const float* __restrict__ a0F, const float* __restrict__ a1F,
                 const float* __restrict__ a2F, const float* __restrict__ a3F,
                 const ushort_t* __restrict__ Hws, const ushort_t* __restrict__ HTws,
                 float* __restrict__ outG) {
  __shared__ __align__(16) ushort_t Hs[LP_ * 128];     // 28672 B, swizzled, rows 0..111
  __shared__ __align__(16) ushort_t Pt[7 * 16 * SP_];  // 30464 B, wave-private ex tiles
  __shared__ float aVf[4 * 128];                       //  2048 B
  // total 61184 B -> 2 blocks/CU

  const int b = blockIdx.x, tid = threadIdx.x;
  const int w = tid / 64, lane = tid & 63, c = lane & 15, q = lane >> 4;
  const ushort_t* Hb  = Hws  + (size_t)b * LP_ * D_;
  const ushort_t* HTb = HTws + (size_t)b * D_ * LQ_;

  // ---- stage a_k + Hs (dense coalesced 16B loads; 4 iters/thread) ----
  for (int u = tid; u < 512; u += 448) {
    int k = u >> 7, d = u & 127;
    const float* ak = (k == 0) ? a0F : (k == 1) ? a1F : (k == 2) ? a2F : a3F;
    aVf[u] = ak[d];
  }
  for (int u = tid; u < LP_ * 16; u += 448) {          // (row, 8-short chunk)
    int r = u >> 4, ch = u & 15;
    *(us8*)&Hs[sw(r, ch * 8)] = *(const us8*)&Hb[r * D_ + ch * 8];
  }
  __syncthreads();                                     // the only barrier

  // ---- A-side: h row (m = c of tile w), a_k folded in-register ----
  const int mi = w;
  float hf[4][8];
#pragma unroll
  for (int ks = 0; ks < 4; ++ks) {
    us8 hr = *(const us8*)&Hs[sw(mi * 16 + c, ks * 32 + q * 8)];
#pragma unroll
    for (int jj = 0; jj < 8; ++jj) hf[ks][jj] = b2f(hr[jj]);
  }
  us8 Af[4][4];
#pragma unroll
  for (int k = 0; k < 4; ++k)
#pragma unroll
    for (int ks = 0; ks < 4; ++ks) {
      const float* ap = &aVf[k * 128 + ks * 32 + q * 8];
      f4v av0 = *(const f4v*)ap;
      f4v av1 = *(const f4v*)(ap + 4);
      float p[8];
#pragma unroll
      for (int t = 0; t < 4; ++t) { p[t] = hf[ks][t] * av0[t]; p[4 + t] = hf[ks][4 + t] * av1[t]; }
      Af[k][ks] = pack8(p);
    }

  // ---- E over 7 j-tiles; adj direct from global; select+leaky -> lg ----
  float lg[7][4];
#pragma unroll
  for (int nt = 0; nt < 7; ++nt) {
    int j = nt * 16 + c;
    int adjv[4];
#pragma unroll
    for (int r = 0; r < 4; ++r) {                      // issue loads before MFMAs
      int i = mi * 16 + q * 4 + r;
      int ic = (i < L_) ? i : L_ - 1, jc = (j < L_) ? j : L_ - 1;
      adjv[r] = adjG[((size_t)b * L_ + ic) * L_ + jc];
      if (i >= L_ || j >= L_) adjv[r] = 0;
    }
    f4 e0 = {0,0,0,0}, e1 = {0,0,0,0}, e2 = {0,0,0,0}, e3 = {0,0,0,0};
#pragma unroll
    for (int ks = 0; ks < 4; ++ks) {
      bf8 bb = __builtin_bit_cast(bf8, *(const us8*)&Hs[sw(nt * 16 + c, ks * 32 + q * 8)]);
      e0 = __builtin_amdgcn_mfma_f32_16x16x32_bf16(__builtin_bit_cast(bf8, Af[0][ks]), bb, e0, 0, 0, 0);
      e1 = __builtin_amdgcn_mfma_f32_16x16x32_bf16(__builtin_bit_cast(bf8, Af[1][ks]), bb, e1, 0, 0, 0);
      e2 = __builtin_amdgcn_mfma_f32_16x16x32_bf16(__builtin_bit_cast(bf8, Af[2][ks]), bb, e2, 0, 0, 0);
      e3 = __builtin_amdgcn_mfma_f32_16x16x32_bf16(__builtin_bit_cast(bf8, Af[3][ks]), bb, e3, 0, 0, 0);
    }
#pragma unroll
    for (int r = 0; r < 4; ++r) {
      int t = adjv[r];
      float e = (t == 1) ? e0[r] : (t == 2) ? e1[r] : (t == 3) ? e2[r] : e3[r];
      e = (e > 0.f) ? e : 0.2f * e;                    // leaky_relu(0.2)
      lg[nt][r] = (t >= 1) ? e : -9e15f;
    }
  }

  // ---- softmax: store UNNORMALIZED ex to Pt; keep inv[r] in registers ----
  ushort_t* Pw = Pt + w * 16 * SP_;
  float inv[4];
#pragma unroll
  for (int r = 0; r < 4; ++r) {
    float m = lg[0][r];
#pragma unroll
    for (int nt = 1; nt < 7; ++nt) m = fmaxf(m, lg[nt][r]);
#pragma unroll
    for (int off = 1; off <= 8; off <<= 1) m = fmaxf(m, __shfl_xor(m, off, 64));
    float ex[7], s = 0.f;
#pragma unroll
    for (int nt = 0; nt < 7; ++nt) { ex[nt] = __expf(lg[nt][r] - m); s += ex[nt]; }
#pragma unroll
    for (int off = 1; off <= 8; off <<= 1) s += __shfl_xor(s, off, 64);
    inv[r] = 1.0f / s;
    int row = q * 4 + r;
#pragma unroll
    for (int nt = 0; nt < 7; ++nt) Pw[row * SP_ + nt * 16 + c] = f2b(ex[nt]);
  }
#pragma unroll
  for (int t = 0; t < 4; ++t) Pw[c * SP_ + 112 + q * 4 + t] = 0;   // zero K-pad (avoid NaN*0)

  // ---- PV: Pf from own-wave Pt (lgkmcnt only), OB dense from HTws global ----
  us8 Pf[4];
#pragma unroll
  for (int ks = 0; ks < 4; ++ks)
    Pf[ks] = *(const us8*)&Pw[c * SP_ + ks * 32 + q * 8];
#pragma unroll
  for (int nt2 = 0; nt2 < 8; ++nt2) {
    f4 a = {0,0,0,0};
#pragma unroll
    for (int ks = 0; ks < 4; ++ks) {
      bf8 ob = __builtin_bit_cast(bf8, *(const us8*)&HTb[(nt2 * 16 + c) * LQ_ + ks * 32 + q * 8]);
      a = __builtin_amdgcn_mfma_f32_16x16x32_bf16(__builtin_bit_cast(bf8, Pf[ks]), ob, a, 0, 0, 0);
    }
    // C/D: col=c (=d in tile), row=q*4+r (=i in tile); scale by inv[r] (same rows)
#pragma unroll
    for (int r = 0; r < 4; ++r) {
      int i = mi * 16 + q * 4 + r;
      if (i < L_) outG[((size_t)b * L_ + i) * (size_t)D_ + nt2 * 16 + c] = a[r] * inv[r];
    }
  }
}

extern "C" void kernel_launch(void* const* d_in, const int* in_sizes, int n_in,
                              void* d_out, int out_size, void* d_ws, size_t ws_size,
                              hipStream_t stream) {
  (void)out_size; (void)ws_size;   // uses 31,457,280 B of d_ws (validated in R5)
  const int* inp = nullptr; const int* adj = nullptr;
  const float* emb = nullptr; const float* aP[4] = {nullptr, nullptr, nullptr, nullptr};
  int na = 0;
  for (int i = 0; i < n_in; ++i) {
    int s = in_sizes[i];
    if (s == 25600000)            emb = (const float*)d_in[i];
    else if (s == 5120000)        adj = (const int*)d_in[i];
    else if (s == 128 && na < 4)  aP[na++] = (const float*)d_in[i];
    else if (s == 51200 && !inp)  inp = (const int*)d_in[i];
  }
  ushort_t* Hws  = (ushort_t*)d_ws;
  ushort_t* HTws = (ushort_t*)((char*)d_ws + HT_OFFSET);
  prep_kernel<<<dim3(B_), dim3(256), 0, stream>>>(inp, emb, Hws, HTws);
  attn_kernel<<<dim3(B_), dim3(448), 0, stream>>>(
      adj, aP[0], aP[1], aP[2], aP[3], Hws, HTws, (float*)d_out);
}